// Round 15
// baseline (113.737 us; speedup 1.0000x reference)
//
#include <hip/hip_runtime.h>
#include <hip/hip_bf16.h>

// ---- static sizes (match reference) ----
#define BATCH   256
#define N_PER   64
#define NNODES  (BATCH * N_PER)        // 16384
#define HID     32
#define NF      6
#define OUTF    2
#define P_PER   (N_PER * (N_PER - 1))  // 4032
#define E_TOT   (BATCH * P_PER)        // 1032192

// output layout (f32 elements): out | H | edge_index[2,E] | edge_weight[E]
#define O_OUT 0
#define O_H   (NNODES * OUTF)           // 32768
#define O_EI  (O_H + NNODES * HID)      // 557056
#define O_EW  (O_EI + 2 * E_TOT)        // 2621440

#define NSTR 33   // padded node-array stride (bank-conflict-free column reads)

__global__ __launch_bounds__(1024) void ope_fused_v3(
    const float* __restrict__ node_x,
    const float* __restrict__ h_in,
    const float* __restrict__ Wn,  const float* __restrict__ bn,
    const float* __restrict__ We1, const float* __restrict__ be1,
    const float* __restrict__ We2, const float* __restrict__ be2,
    const float* __restrict__ Wz,  const float* __restrict__ bz,
    const float* __restrict__ Wr,  const float* __restrict__ br,
    const float* __restrict__ Wh,  const float* __restrict__ bh,
    const float* __restrict__ Wf,  const float* __restrict__ bf,
    float* __restrict__ out)
{
    // folded GRU weights, row-major [64][32] (rows 0..31: x-part, 32..63: h-part)
    __shared__ float sWz[2048], sWr[2048], sWh[2048];
    __shared__ float sWe1[64 * 65];     // padded stride 65
    __shared__ float sWe2[64], sbe1[64], sWf[64];
    __shared__ float sWn[NF * HID];
    __shared__ float sbn[HID], sbz[HID], sbr[HID], sbh[HID];
    __shared__ float sbf[OUTF];
    __shared__ float sw[64];            // collapsed edge weights: u|v
    __shared__ float sc_;               // collapsed edge bias
    __shared__ float sx[N_PER * NSTR];  // x
    __shared__ float sh[N_PER * NSTR];  // h
    __shared__ float shr[N_PER * NSTR]; // h*R
    __shared__ float sa[N_PER], sb[N_PER];

    const int t = threadIdx.x;
    const int g = blockIdx.x;

    // ================= P1: stage + fold all weights =================
    #pragma unroll 2
    for (int i = t; i < 2048; i += 1024) {
        sWz[i] = Wz[i] + Wz[2048 + i];
        sWr[i] = Wr[i] + Wr[2048 + i];
        sWh[i] = Wh[i] + Wh[2048 + i];
    }
    #pragma unroll 4
    for (int i = t; i < 4096; i += 1024)
        sWe1[(i >> 6) * 65 + (i & 63)] = We1[i];
    if (t < NF * HID) sWn[t] = Wn[t];
    if (t < 64) { sWe2[t] = We2[t]; sbe1[t] = be1[t]; sWf[t] = Wf[t]; }
    if (t < HID) { sbn[t] = bn[t]; sbz[t] = bz[t]; sbr[t] = br[t]; sbh[t] = bh[t]; }
    if (t < OUTF) sbf[t] = bf[t];
    __syncthreads();

    const int k   = t & 31;    // hidden index
    const int row = t >> 5;    // 0..31 ; this thread's nodes: row, row+32

    // ================= P2: x = node_x@Wn + bn ; stage h ; sw/c =======
    float xq[2];
    #pragma unroll
    for (int q = 0; q < 2; ++q) {
        const int n = row + 32 * q;
        const float* nx = node_x + (size_t)(g * N_PER + n) * NF;
        float acc = sbn[k];
        #pragma unroll
        for (int f = 0; f < NF; ++f) acc += nx[f] * sWn[f * HID + k];
        xq[q] = acc;
        sx[n * NSTR + k] = acc;
        sh[n * NSTR + k] = h_in[(size_t)(g * N_PER + n) * HID + k];
    }
    if (t < 64) {                       // u|v from LDS (conflict-free, parallel)
        float s = 0.f;
        #pragma unroll
        for (int m = 0; m < 64; ++m) s += sWe1[t * 65 + m] * sWe2[m];
        sw[t] = s;
    } else if (t == 64) {               // collapsed bias
        float s = be2[0];
        #pragma unroll
        for (int m = 0; m < 64; ++m) s += sbe1[m] * sWe2[m];
        sc_ = s;
    }
    __syncthreads();

    // ================= P3: edge dots (shfl) + gates Z,R =============
    {   // a[n] = x_n . u , b[n] = x_n . v  via 32-lane butterflies
        float pa0 = xq[0] * sw[k],       pb0 = xq[0] * sw[32 + k];
        float pa1 = xq[1] * sw[k],       pb1 = xq[1] * sw[32 + k];
        #pragma unroll
        for (int m = 16; m >= 1; m >>= 1) {
            pa0 += __shfl_xor(pa0, m); pb0 += __shfl_xor(pb0, m);
            pa1 += __shfl_xor(pa1, m); pb1 += __shfl_xor(pb1, m);
        }
        if (k == 0) { sa[row] = pa0; sb[row] = pb0; sa[row + 32] = pa1; sb[row + 32] = pb1; }
    }
    float az[2], ar[2];
    az[0] = az[1] = sbz[k];
    ar[0] = ar[1] = sbr[k];
    for (int d = 0; d < HID; ++d) {
        const float wzx = sWz[d * HID + k], wzh = sWz[(HID + d) * HID + k];
        const float wrx = sWr[d * HID + k], wrh = sWr[(HID + d) * HID + k];
        #pragma unroll
        for (int q = 0; q < 2; ++q) {
            const int n = row + 32 * q;
            const float xv = sx[n * NSTR + d];
            const float hv = sh[n * NSTR + d];
            az[q] += xv * wzx + hv * wzh;
            ar[q] += xv * wrx + hv * wrh;
        }
    }
    float zreg[2];
    #pragma unroll
    for (int q = 0; q < 2; ++q) {
        const int n = row + 32 * q;
        const float Z = 1.f / (1.f + expf(-az[q]));
        const float R = 1.f / (1.f + expf(-ar[q]));
        zreg[q] = Z;
        shr[n * NSTR + k] = sh[n * NSTR + k] * R;
    }
    __syncthreads();

    // ======== P4: H_tilde, H, H-store, proj (shfl) ; edge streams ====
    float ah[2];
    ah[0] = ah[1] = sbh[k];
    for (int d = 0; d < HID; ++d) {
        const float whx = sWh[d * HID + k], whh = sWh[(HID + d) * HID + k];
        #pragma unroll
        for (int q = 0; q < 2; ++q) {
            const int n = row + 32 * q;
            ah[q] += sx[n * NSTR + d] * whx + shr[n * NSTR + d] * whh;
        }
    }
    #pragma unroll
    for (int q = 0; q < 2; ++q) {
        const int n = row + 32 * q;
        const float Ht = tanhf(ah[q]);
        const float Z  = zreg[q];
        const float Hv = Z * sh[n * NSTR + k] + (1.f - Z) * Ht;
        out[O_H + (size_t)(g * N_PER + n) * HID + k] = Hv;
        // projection via butterfly: relu(H) @ Wf + bf (2 outputs)
        const float rh = fmaxf(Hv, 0.f);
        float s0 = rh * sWf[k * OUTF + 0];
        float s1 = rh * sWf[k * OUTF + 1];
        #pragma unroll
        for (int m = 16; m >= 1; m >>= 1) {
            s0 += __shfl_xor(s0, m);
            s1 += __shfl_xor(s1, m);
        }
        if (k == 0)
            *(float2*)&out[O_OUT + (size_t)(g * N_PER + n) * OUTF] =
                make_float2(s0 + sbf[0], s1 + sbf[1]);
    }
    // edges: weight = relu(a_i + b_j + c) + index rows (sa/sb ready: P3 barrier)
    if (t < 1008) {
        const float c  = sc_;
        const float gb = (float)(g * N_PER);
        const int p0 = t * 4;
        float4 w4, i4, j4;
        #pragma unroll
        for (int u = 0; u < 4; ++u) {
            const int p = p0 + u;
            const int i = (p * 16645) >> 20;    // exact floor(p/63), p<4032
            const int r = p - i * 63;
            const int j = r + (r >= i ? 1 : 0);
            (&w4.x)[u] = fmaxf(sa[i] + sb[j] + c, 0.f);
            (&i4.x)[u] = gb + (float)i;
            (&j4.x)[u] = gb + (float)j;
        }
        const size_t e = (size_t)g * P_PER + p0;
        *(float4*)&out[O_EW + e]         = w4;
        *(float4*)&out[O_EI + e]         = i4;
        *(float4*)&out[O_EI + E_TOT + e] = j4;
    }
}

extern "C" void kernel_launch(void* const* d_in, const int* in_sizes, int n_in,
                              void* d_out, int out_size, void* d_ws, size_t ws_size,
                              hipStream_t stream) {
    // f32 everywhere, dict pointer order (established rounds 1-13).
    ope_fused_v3<<<dim3(BATCH), dim3(1024), 0, stream>>>(
        (const float*)d_in[0],   // node_x
        (const float*)d_in[2],   // h
        (const float*)d_in[3],   // Wn
        (const float*)d_in[4],   // bn
        (const float*)d_in[5],   // We1
        (const float*)d_in[6],   // be1
        (const float*)d_in[7],   // We2
        (const float*)d_in[8],   // be2
        (const float*)d_in[9],   // Wz
        (const float*)d_in[10],  // bz
        (const float*)d_in[11],  // Wr
        (const float*)d_in[12],  // br
        (const float*)d_in[13],  // Wh
        (const float*)d_in[14],  // bh
        (const float*)d_in[15],  // Wf
        (const float*)d_in[16],  // bf
        (float*)d_out);
}